// Round 2
// baseline (1206.100 us; speedup 1.0000x reference)
//
#include <hip/hip_runtime.h>
#include <stdint.h>

#define DEVI __device__ __forceinline__

typedef __attribute__((ext_vector_type(8))) short short8;
typedef __attribute__((ext_vector_type(4))) float f32x4;
typedef unsigned short u16;
typedef unsigned int u32;

typedef const __attribute__((address_space(1))) void* gas_ptr;
typedef __attribute__((address_space(3))) void* las_ptr;

constexpr int BBATCH = 2;
constexpr int TT  = 1024;
constexpr int BT  = BBATCH * TT;   // 2048 tokens
constexpr int DM  = 1024;
constexpr int NH  = 16;
constexpr int HD  = 64;
constexpr int DFF = 4096;
constexpr int NV  = 32000;
constexpr int NL  = 4;

DEVI u16 f2b(float f) {
  u32 u = __builtin_bit_cast(u32, f);
  u = (u + 0x7fffu + ((u >> 16) & 1u)) >> 16;
  return (u16)u;
}
DEVI float b2f(u16 h) { return __builtin_bit_cast(float, (u32)h << 16); }

DEVI void gld16(const void* g, void* l) {
  __builtin_amdgcn_global_load_lds((gas_ptr)g, (las_ptr)l, 16, 0, 0);
}

DEVI float wave_sum(float v) {
#pragma unroll
  for (int off = 32; off; off >>= 1) v += __shfl_xor(v, off);
  return v;
}
DEVI float wave_max(float v) {
#pragma unroll
  for (int off = 32; off; off >>= 1) v = fmaxf(v, __shfl_xor(v, off));
  return v;
}
DEVI float block_sum(float v, float* sb) {
  v = wave_sum(v);
  int lane = threadIdx.x & 63, wid = threadIdx.x >> 6;
  __syncthreads();
  if (lane == 0) sb[wid] = v;
  __syncthreads();
  return sb[0] + sb[1] + sb[2] + sb[3];
}
DEVI float block_max(float v, float* sb) {
  v = wave_max(v);
  int lane = threadIdx.x & 63, wid = threadIdx.x >> 6;
  __syncthreads();
  if (lane == 0) sb[wid] = v;
  __syncthreads();
  return fmaxf(fmaxf(sb[0], sb[1]), fmaxf(sb[2], sb[3]));
}

DEVI float gelu_f(float x) {
  float u = 0.7978845608028654f * (x + 0.044715f * x * x * x);
  float e = __expf(2.0f * u);            // gelu = x * sigmoid(2u)
  return x * (1.0f - 1.0f / (e + 1.0f));
}

// ---------------- weight transpose+convert: f32 [K][N] -> bf16 [N][K] ----------------
__global__ __launch_bounds__(256) void wt_transpose(const float* __restrict__ in,
                                                    u16* __restrict__ out, int K, int N) {
  __shared__ float t[32][33];
  int n0 = blockIdx.x * 32, k0 = blockIdx.y * 32;
  int tx = threadIdx.x, ty = threadIdx.y;
#pragma unroll
  for (int i = 0; i < 4; ++i)
    t[ty + 8 * i][tx] = in[(size_t)(k0 + ty + 8 * i) * N + n0 + tx];
  __syncthreads();
#pragma unroll
  for (int i = 0; i < 4; ++i)
    out[(size_t)(n0 + ty + 8 * i) * K + k0 + tx] = f2b(t[tx][ty + 8 * i]);
}

// ---------------- V transpose: qkv bf16 [b*T][3D] (v slice) -> vT [bh][64][1024] ----------------
__global__ __launch_bounds__(256) void v_transpose(const u16* __restrict__ qkv,
                                                   u16* __restrict__ vT) {
  __shared__ u16 t[32][33];
  int bh = blockIdx.z, b = bh >> 4, h = bh & 15;
  int d0 = blockIdx.x * 32, t0 = blockIdx.y * 32;
  int tx = threadIdx.x, ty = threadIdx.y;
  const u16* src = qkv + (size_t)b * TT * 3 * DM + 2 * DM + h * HD;
#pragma unroll
  for (int i = 0; i < 4; ++i)
    t[ty + 8 * i][tx] = src[(size_t)(t0 + ty + 8 * i) * (3 * DM) + d0 + tx];
  __syncthreads();
  u16* dst = vT + (size_t)bh * HD * TT;
#pragma unroll
  for (int i = 0; i < 4; ++i)
    dst[(size_t)(d0 + ty + 8 * i) * TT + t0 + tx] = t[tx][ty + 8 * i];
}

// ---------------- embedding gather + LayerNorm -> x f32 ----------------
__global__ __launch_bounds__(256) void embed_ln_k(const int* __restrict__ idx,
                                                  const float* __restrict__ tok,
                                                  const float* __restrict__ g,
                                                  const float* __restrict__ b,
                                                  float* __restrict__ x) {
  __shared__ float sb[4];
  int row = blockIdx.x, tid = threadIdx.x;
  float4 v = ((const float4*)(tok + (size_t)idx[row] * DM))[tid];
  float s = block_sum(v.x + v.y + v.z + v.w, sb);
  float m = s * (1.0f / DM);
  float dx = v.x - m, dy = v.y - m, dz = v.z - m, dw = v.w - m;
  float q = block_sum(dx * dx + dy * dy + dz * dz + dw * dw, sb);
  float rs = rsqrtf(q * (1.0f / DM) + 1e-5f);
  float4 gg = ((const float4*)g)[tid];
  float4 bb = ((const float4*)b)[tid];
  float4 o = make_float4(dx * rs * gg.x + bb.x, dy * rs * gg.y + bb.y,
                         dz * rs * gg.z + bb.z, dw * rs * gg.w + bb.w);
  ((float4*)(x + (size_t)row * DM))[tid] = o;
}

// ---------------- final LayerNorm -> bf16 ----------------
__global__ __launch_bounds__(256) void final_ln_k(const float* __restrict__ x,
                                                  const float* __restrict__ g,
                                                  const float* __restrict__ b,
                                                  u16* __restrict__ xf) {
  __shared__ float sb[4];
  int row = blockIdx.x, tid = threadIdx.x;
  float4 v = ((const float4*)(x + (size_t)row * DM))[tid];
  float s = block_sum(v.x + v.y + v.z + v.w, sb);
  float m = s * (1.0f / DM);
  float dx = v.x - m, dy = v.y - m, dz = v.z - m, dw = v.w - m;
  float q = block_sum(dx * dx + dy * dy + dz * dz + dw * dw, sb);
  float rs = rsqrtf(q * (1.0f / DM) + 1e-5f);
  float4 gg = ((const float4*)g)[tid];
  float4 bb = ((const float4*)b)[tid];
  u32 lo = (u32)f2b(dx * rs * gg.x + bb.x) | ((u32)f2b(dy * rs * gg.y + bb.y) << 16);
  u32 hi = (u32)f2b(dz * rs * gg.z + bb.z) | ((u32)f2b(dw * rs * gg.w + bb.w) << 16);
  ((uint2*)(xf + (size_t)row * DM))[tid] = make_uint2(lo, hi);
}

// ---------------- RMSNorm f32 -> bf16 ----------------
__global__ __launch_bounds__(256) void rmsnorm_k(const float* __restrict__ x,
                                                 const float* __restrict__ w,
                                                 u16* __restrict__ h) {
  __shared__ float sb[4];
  int row = blockIdx.x, tid = threadIdx.x;
  float4 v = ((const float4*)(x + (size_t)row * DM))[tid];
  float q = block_sum(v.x * v.x + v.y * v.y + v.z * v.z + v.w * v.w, sb);
  float rs = rsqrtf(q * (1.0f / DM) + 1.1920928955078125e-7f);
  float4 ww = ((const float4*)w)[tid];
  u32 lo = (u32)f2b(v.x * rs * ww.x) | ((u32)f2b(v.y * rs * ww.y) << 16);
  u32 hi = (u32)f2b(v.z * rs * ww.z) | ((u32)f2b(v.w * rs * ww.w) << 16);
  ((uint2*)(h + (size_t)row * DM))[tid] = make_uint2(lo, hi);
}

// ---------------- causal row softmax, in place on bf16 S rows of length 1024 ----------------
// QK writes only tiles with bcol <= brow (others skipped). For row r, valid data
// exists for cols < 128*((r>>7)+1); we process only that range, mask col>r, and
// write zeros there (PV's causal trim reads up to the 128-tile boundary).
__global__ __launch_bounds__(256) void softmax_k(u16* __restrict__ S) {
  __shared__ float sb[4];
  size_t rowg = blockIdx.x;
  int r = (int)(rowg & (TT - 1));
  int limit = ((r >> 7) + 1) << 5;          // threads with tid < limit hold valid quads
  u16* p = S + rowg * TT;
  int tid = threadIdx.x;
  bool act = tid < limit;
  int c = tid * 4;
  float v0 = -3e38f, v1 = -3e38f, v2 = -3e38f, v3 = -3e38f;
  if (act) {
    uint2 d = ((const uint2*)p)[tid];
    float a0 = b2f((u16)(d.x & 0xffff)), a1 = b2f((u16)(d.x >> 16));
    float a2 = b2f((u16)(d.y & 0xffff)), a3 = b2f((u16)(d.y >> 16));
    v0 = (c + 0 <= r) ? a0 : -3e38f;
    v1 = (c + 1 <= r) ? a1 : -3e38f;
    v2 = (c + 2 <= r) ? a2 : -3e38f;
    v3 = (c + 3 <= r) ? a3 : -3e38f;
  }
  float m = block_max(fmaxf(fmaxf(v0, v1), fmaxf(v2, v3)), sb);
  float e0 = __expf(v0 - m), e1 = __expf(v1 - m), e2 = __expf(v2 - m), e3 = __expf(v3 - m);
  float s = block_sum(e0 + e1 + e2 + e3, sb);
  if (act) {
    float inv = 1.0f / s;
    u32 lo = (u32)f2b(e0 * inv) | ((u32)f2b(e1 * inv) << 16);
    u32 hi = (u32)f2b(e2 * inv) | ((u32)f2b(e3 * inv) << 16);
    ((uint2*)p)[tid] = make_uint2(lo, hi);
  }
}

// ---------------- GEMM epilogue variants ----------------
enum { EPI_BF16 = 0, EPI_GELU = 1, EPI_ADDF32 = 2, EPI_F32 = 3, EPI_QK = 4 };

// ---------------- 2-phase 128-tile GEMM (validated r1) ----------------
template <int BM, int BN, int WM, int WN, int EPI>
__global__ __launch_bounds__(256, 2) void gemm_bt(
    const u16* __restrict__ A, int lda, const u16* __restrict__ Bt, int ldb,
    const float* __restrict__ bias, void* __restrict__ C, int ldc,
    float* __restrict__ resid, int K, int causalTrim,
    int aDiv, long long aOuter, int aInner,
    int bDiv, long long bOuter, int bInner,
    int cDiv, long long cOuter, int cInner) {
  constexpr int BK = 64;                       // 128 bytes per LDS row
  constexpr int NW = WM * WN;                  // 4 waves
  constexpr int FM = BM / WM / 16, FN = BN / WN / 16;
  constexpr int ABYTES = BM * BK * 2, BBYTES = BN * BK * 2;
  constexpr int ACH = ABYTES / 1024, BCH = BBYTES / 1024, NCH = ACH + BCH;
  extern __shared__ __align__(16) char smem[];

  const int tid = threadIdx.x, lane = tid & 63, wid = tid >> 6;
  const int brow = blockIdx.y * BM, bcol = blockIdx.x * BN;
  const int batch = blockIdx.z;

  const long long cOff = (long long)(batch / cDiv) * cOuter + (long long)(batch % cDiv) * cInner;

  if constexpr (EPI == EPI_QK) {
    if (bcol > brow + (BM - 1)) return;  // fully masked: softmax never reads it
  }

  const u16* Ab = A + (long long)(batch / aDiv) * aOuter + (long long)(batch % aDiv) * aInner;
  const u16* Bb = Bt + (long long)(batch / bDiv) * bOuter + (long long)(batch % bDiv) * bInner;

  int nt = K >> 6;
  if (causalTrim) { int mx = (blockIdx.y + 1) * (BM / BK); nt = nt < mx ? nt : mx; }

  const int widm = wid / WN, widn = wid % WN;
  const int rm0 = widm * (BM / WM), cn0 = widn * (BN / WN);

  f32x4 acc[FM][FN] = {};

  const int swq16 = (((lane & 7) ^ ((lane >> 3) & 7)) << 4);
  const int lrow8 = lane >> 3;

  auto stage = [&](int buf, int kt) {
    char* base = smem + buf * (ABYTES + BBYTES);
    const char* Ag = (const char*)Ab;
    const char* Bg = (const char*)Bb;
    long long kOff = (long long)kt * 128 + swq16;
#pragma unroll
    for (int ci = 0; ci < NCH / NW; ++ci) {
      int c = wid + ci * NW;
      if (c < ACH) {
        int r = c * 8 + lrow8;
        gld16(Ag + (long long)(brow + r) * (lda * 2) + kOff, base + c * 1024 + lane * 16);
      } else {
        int r = (c - ACH) * 8 + lrow8;
        gld16(Bg + (long long)(bcol + r) * (ldb * 2) + kOff,
              base + ABYTES + (c - ACH) * 1024 + lane * 16);
      }
    }
  };

  auto compute = [&](int buf) {
    char* baseA = smem + buf * (ABYTES + BBYTES);
    char* baseB = baseA + ABYTES;
#pragma unroll
    for (int ks = 0; ks < 2; ++ks) {
      short8 af[FM], bv[FN];
#pragma unroll
      for (int i = 0; i < FM; ++i) {
        int r = rm0 + i * 16 + (lane & 15);
        int cq = ((ks << 2) + (lane >> 4)) ^ (r & 7);
        af[i] = *(const short8*)(baseA + r * 128 + (cq << 4));
      }
#pragma unroll
      for (int j = 0; j < FN; ++j) {
        int r = cn0 + j * 16 + (lane & 15);
        int cq = ((ks << 2) + (lane >> 4)) ^ (r & 7);
        bv[j] = *(const short8*)(baseB + r * 128 + (cq << 4));
      }
#pragma unroll
      for (int i = 0; i < FM; ++i)
#pragma unroll
        for (int j = 0; j < FN; ++j)
          acc[i][j] = __builtin_amdgcn_mfma_f32_16x16x32_bf16(af[i], bv[j], acc[i][j], 0, 0, 0);
    }
  };

  stage(0, 0);
  __syncthreads();
  int cur = 0;
  for (int t = 0; t < nt; ++t) {
    if (t + 1 < nt) stage(cur ^ 1, t + 1);
    compute(cur);
    __syncthreads();
    cur ^= 1;
  }

  const int r0 = brow + rm0 + ((lane >> 4) << 2);
  const int c0 = bcol + cn0 + (lane & 15);
#pragma unroll
  for (int i = 0; i < FM; ++i) {
#pragma unroll
    for (int j = 0; j < FN; ++j) {
#pragma unroll
      for (int r = 0; r < 4; ++r) {
        int row = r0 + i * 16 + r;
        int col = c0 + j * 16;
        float v = acc[i][j][r];
        if constexpr (EPI == EPI_QK) {
          int hh = batch & 15;
          float slope = exp2f(-0.5f * (hh + 1));
          float val = (col <= row) ? (v * 0.125f - slope * (float)(row - col)) : -1e30f;
          ((u16*)C + cOff)[(size_t)row * ldc + col] = f2b(val);
        } else if constexpr (EPI == EPI_BF16) {
          float val = v + (bias ? bias[col] : 0.0f);
          ((u16*)C + cOff)[(size_t)row * ldc + col] = f2b(val);
        } else if constexpr (EPI == EPI_GELU) {
          ((u16*)C)[(size_t)row * ldc + col] = f2b(gelu_f(v + bias[col]));
        } else if constexpr (EPI == EPI_ADDF32) {
          size_t o = (size_t)row * ldc + col;
          resid[o] += v + bias[col];
        } else {
          ((float*)C)[(size_t)row * ldc + col] = v + bias[col];
        }
      }
    }
  }
}

// ---------------- 8-phase 256x256 GEMM (T1+T2+T3+T4+T5) ----------------
// 8 waves (2M x 4N), BK=64, double-buffered 128KiB LDS, per-wave 128x64 output.
// Region-free staging ledger (iter i computes tiles u=2i buf0 [p1-4], v=2i+1 buf1 [p5-8]):
//   p1: stage (2i+1).A h0 -> buf1.A (free since prev p8 barrier)
//   p2: stage (2i+1).A h1
//   p3: stage (2i+2).B h0 -> buf0.B (B fully consumed at p1, barrier-published)
//   p4: stage (2i+2).B h1 ; vmcnt(4) -> completes prev p7,p8 + p1,p2 = tile v's B+A
//   p5: stage (2i+2).A h0 -> buf0.A (A consumed p1-4)
//   p6: stage (2i+2).A h1
//   p7: stage (2i+3).B h0 -> buf1.B (consumed at p5)
//   p8: stage (2i+3).B h1 ; vmcnt(4) -> completes p3-p6 = tile 2i+2's B+A
// Last iter: p3..p8 stages guarded off; p4 uses vmcnt(0); p8 no wait.
template <int EPI>
__global__ __launch_bounds__(512, 2) void gemm8(
    const u16* __restrict__ A, int lda, const u16* __restrict__ Bt, int ldb,
    const float* __restrict__ bias, void* __restrict__ C, int ldc, int K, int nby) {
  __shared__ __align__(16) char smem[2][2][32768];  // [buf][A=0/B=1][256 rows x 128B]
  const int tid = threadIdx.x, lane = tid & 63;
  const int wid = tid >> 6, wm = wid >> 2, wn = wid & 3;

  // T1: bijective XCD swizzle, then column-major tile order (B-panel L2 reuse)
  const int nb = gridDim.x;
  const int q8 = nb >> 3, r8 = nb & 7;
  const int xcd = blockIdx.x & 7, lin = blockIdx.x >> 3;
  const int idx = (xcd < r8 ? xcd * (q8 + 1) : r8 * (q8 + 1) + (xcd - r8) * q8) + lin;
  const int brow = (idx % nby) * 256, bcol = (idx / nby) * 256;

  const int nt = K >> 6, niter = nt >> 1;

  const int srow = tid >> 3, sq = tid & 7;
  auto stage = [&](int buf, int isB, int half, int kt) {
    const u16* G = isB ? Bt : A;
    const int ld = isB ? ldb : lda;
    const int base = isB ? bcol : brow;
    char* L = &smem[buf][isB][half * 16384];
#pragma unroll
    for (int l = 0; l < 2; ++l) {
      int rl = half * 128 + l * 64 + srow;
      gld16((const char*)G + (size_t)(base + rl) * (ld * 2) + kt * 128 + ((sq ^ (rl & 7)) << 4),
            L + l * 8192 + tid * 16);
    }
  };

  short8 bfr[4][2], afr[2][2];
  f32x4 acc[8][4] = {};

  // prologue: tile0.A h0,h1 + tile0.B h0,h1 + tile1.B h0,h1
  stage(0, 0, 0, 0); stage(0, 0, 1, 0);
  stage(0, 1, 0, 0); stage(0, 1, 1, 0);
  stage(1, 1, 0, 1); stage(1, 1, 1, 1);
  asm volatile("s_waitcnt vmcnt(0)" ::: "memory");
  __builtin_amdgcn_s_barrier();

  for (int i = 0; i < niter; ++i) {
    const bool full = (i + 1 < niter);
    const int t2 = 2 * i + 2, t3 = 2 * i + 3;
#pragma unroll
    for (int h = 0; h < 2; ++h) {
#pragma unroll
      for (int qd = 0; qd < 4; ++qd) {
        // ds-load register subtile from compute buf h
        if (qd == 0) {
#pragma unroll
          for (int j = 0; j < 4; ++j)
#pragma unroll
            for (int ks = 0; ks < 2; ++ks) {
              int r = wn * 64 + j * 16 + (lane & 15);
              int q = ((ks << 2) + (lane >> 4)) ^ (r & 7);
              bfr[j][ks] = *(const short8*)&smem[h][1][r * 128 + q * 16];
            }
        }
#pragma unroll
        for (int f = 0; f < 2; ++f)
#pragma unroll
          for (int ks = 0; ks < 2; ++ks) {
            int r = wm * 128 + (qd * 2 + f) * 16 + (lane & 15);
            int q = ((ks << 2) + (lane >> 4)) ^ (r & 7);
            afr[f][ks] = *(const short8*)&smem[h][0][r * 128 + q * 16];
          }
        // stage one half-tile per phase (see ledger above)
        if (h == 0) {
          if (qd == 0) stage(1, 0, 0, 2 * i + 1);
          else if (qd == 1) stage(1, 0, 1, 2 * i + 1);
          else if (qd == 2) { if (full) stage(0, 1, 0, t2); }
          else              { if (full) stage(0, 1, 1, t2); }
        } else {
          if (qd == 0)      { if (full) stage(0, 0, 0, t2); }
          else if (qd == 1) { if (full) stage(0, 0, 1, t2); }
          else if (qd == 2) { if (full) stage(1, 1, 0, t3); }
          else              { if (full) stage(1, 1, 1, t3); }
        }
        if (qd == 3) {
          if (full) asm volatile("s_waitcnt vmcnt(4)" ::: "memory");
          else if (h == 0) asm volatile("s_waitcnt vmcnt(0)" ::: "memory");
        }
        __builtin_amdgcn_s_barrier();
        asm volatile("s_waitcnt lgkmcnt(0)" ::: "memory");
        __builtin_amdgcn_s_setprio(1);
#pragma unroll
        for (int f = 0; f < 2; ++f)
#pragma unroll
          for (int j = 0; j < 4; ++j)
#pragma unroll
            for (int ks = 0; ks < 2; ++ks)
              acc[qd * 2 + f][j] = __builtin_amdgcn_mfma_f32_16x16x32_bf16(
                  afr[f][ks], bfr[j][ks], acc[qd * 2 + f][j], 0, 0, 0);
        __builtin_amdgcn_s_setprio(0);
        __builtin_amdgcn_s_barrier();
      }
    }
  }

  // epilogue: D row=(lane>>4)*4+reg, col=lane&15
  const int r0 = brow + wm * 128 + ((lane >> 4) << 2);
  const int c0 = bcol + wn * 64 + (lane & 15);
#pragma unroll
  for (int fi = 0; fi < 8; ++fi) {
#pragma unroll
    for (int j = 0; j < 4; ++j) {
      int col = c0 + j * 16;
      float bv = bias[col];
#pragma unroll
      for (int r = 0; r < 4; ++r) {
        int row = r0 + fi * 16 + r;
        float v = acc[fi][j][r] + bv;
        if constexpr (EPI == EPI_F32)
          ((float*)C)[(size_t)row * ldc + col] = v;
        else if constexpr (EPI == EPI_GELU)
          ((u16*)C)[(size_t)row * ldc + col] = f2b(gelu_f(v));
        else
          ((u16*)C)[(size_t)row * ldc + col] = f2b(v);
      }
    }
  }
}

extern "C" void kernel_launch(void* const* d_in, const int* in_sizes, int n_in,
                              void* d_out, int out_size, void* d_ws, size_t ws_size,
                              hipStream_t stream) {
  (void)in_sizes; (void)n_in; (void)out_size;
  const int*   idx    = (const int*)d_in[0];
  const float* tok    = (const float*)d_in[1];
  const float* ln_e_g = (const float*)d_in[2];
  const float* ln_e_b = (const float*)d_in[3];
  const float* Wqkv   = (const float*)d_in[4];
  const float* bqkv   = (const float*)d_in[5];
  const float* Wo     = (const float*)d_in[6];
  const float* bo     = (const float*)d_in[7];
  const float* W1     = (const float*)d_in[8];
  const float* b1     = (const float*)d_in[9];
  const float* W2     = (const float*)d_in[10];
  const float* b2     = (const float*)d_in[11];
  const float* n1_w   = (const float*)d_in[12];
  const float* n2_w   = (const float*)d_in[13];
  const float* lnf_g  = (const float*)d_in[14];
  const float* lnf_b  = (const float*)d_in[15];
  const float* Wlm    = (const float*)d_in[16];
  const float* blm    = (const float*)d_in[17];
  float* out = (float*)d_out;

  char* w = (char*)d_ws;
  auto alloc = [&](size_t bytes) { char* p = w; w += (bytes + 255) & ~(size_t)255; return p; };
  float* x   = (float*)alloc((size_t)BT * DM * 4);
  u16* h     = (u16*)alloc((size_t)BT * DM * 2);
  u16* qkv   = (u16*)alloc((size_t)BT * 3 * DM * 2);
  u16* vT    = (u16*)alloc((size_t)BBATCH * NH * HD * TT * 2);
  u16* S     = (u16*)alloc((size_t)BBATCH * NH * TT * TT * 2);
  u16* y     = (u16*)alloc((size_t)BT * DM * 2);
  u16* act   = (u16*)alloc((size_t)BT * DFF * 2);
  u16* xf    = (u16*)alloc((size_t)BT * DM * 2);
  u16* WqkvT = (u16*)alloc((size_t)3 * DM * DM * 2);
  u16* WoT   = (u16*)alloc((size_t)DM * DM * 2);
  u16* W1T   = (u16*)alloc((size_t)DFF * DM * 2);
  u16* W2T   = (u16*)alloc((size_t)DM * DFF * 2);
  u16* WlmT  = (u16*)alloc((size_t)NV * DM * 2);
  if ((size_t)(w - (char*)d_ws) > ws_size) return;

  dim3 t328(32, 8);
  wt_transpose<<<dim3(3 * DM / 32, DM / 32), t328, 0, stream>>>(Wqkv, WqkvT, DM, 3 * DM);
  wt_transpose<<<dim3(DM / 32, DM / 32), t328, 0, stream>>>(Wo, WoT, DM, DM);
  wt_transpose<<<dim3(DFF / 32, DM / 32), t328, 0, stream>>>(W1, W1T, DM, DFF);
  wt_transpose<<<dim3(DM / 32, DFF / 32), t328, 0, stream>>>(W2, W2T, DFF, DM);
  wt_transpose<<<dim3(NV / 32, DM / 32), t328, 0, stream>>>(Wlm, WlmT, DM, NV);

  embed_ln_k<<<BT, 256, 0, stream>>>(idx, tok, ln_e_g, ln_e_b, x);

  constexpr int SM128 = 2 * (128 * 64 * 2 + 128 * 64 * 2);  // 65536
  constexpr int SMPV  = 2 * (128 * 64 * 2 + 64 * 64 * 2);   // 49152

  for (int l = 0; l < NL; ++l) {
    rmsnorm_k<<<BT, 256, 0, stream>>>(x, n1_w, h);
    gemm8<EPI_BF16><<<dim3((3 * DM / 256) * (BT / 256)), 512, 0, stream>>>(
        h, DM, WqkvT, DM, bqkv, qkv, 3 * DM, DM, BT / 256);
    v_transpose<<<dim3(HD / 32, TT / 32, BBATCH * NH), t328, 0, stream>>>(qkv, vT);
    gemm_bt<128, 128, 2, 2, EPI_QK><<<dim3(TT / 128, TT / 128, BBATCH * NH), 256, SM128, stream>>>(
        qkv, 3 * DM, qkv + DM, 3 * DM, nullptr, S, TT, nullptr, HD, 0,
        NH, (long long)TT * 3 * DM, HD,
        NH, (long long)TT * 3 * DM, HD,
        1, (long long)TT * TT, 0);
    softmax_k<<<BBATCH * NH * TT, 256, 0, stream>>>(S);
    gemm_bt<128, 64, 4, 1, EPI_BF16><<<dim3(1, TT / 128, BBATCH * NH), 256, SMPV, stream>>>(
        S, TT, vT, TT, nullptr, y, DM, nullptr, TT, 1,
        1, (long long)TT * TT, 0,
        1, (long long)HD * TT, 0,
        NH, (long long)TT * DM, HD);
    gemm_bt<128, 128, 2, 2, EPI_ADDF32><<<dim3(DM / 128, BT / 128, 1), 256, SM128, stream>>>(
        y, DM, WoT, DM, bo, nullptr, DM, x, DM, 0,
        1, 0, 0, 1, 0, 0, 1, 0, 0);
    rmsnorm_k<<<BT, 256, 0, stream>>>(x, n2_w, h);
    gemm8<EPI_GELU><<<dim3((DFF / 256) * (BT / 256)), 512, 0, stream>>>(
        h, DM, W1T, DM, b1, act, DFF, DM, BT / 256);
    gemm_bt<128, 128, 2, 2, EPI_ADDF32><<<dim3(DM / 128, BT / 128, 1), 256, SM128, stream>>>(
        act, DFF, W2T, DFF, b2, nullptr, DM, x, DFF, 0,
        1, 0, 0, 1, 0, 0, 1, 0, 0);
  }

  final_ln_k<<<BT, 256, 0, stream>>>(x, lnf_g, lnf_b, xf);
  gemm8<EPI_F32><<<dim3((NV / 256) * (BT / 256)), 512, 0, stream>>>(
      xf, DM, WlmT, DM, blm, out, NV, DM, BT / 256);
}

// Round 3
// 974.398 us; speedup vs baseline: 1.2378x; 1.2378x over previous
//
#include <hip/hip_runtime.h>
#include <stdint.h>

#define DEVI __device__ __forceinline__

typedef __attribute__((ext_vector_type(8))) short short8;
typedef __attribute__((ext_vector_type(4))) float f32x4;
typedef unsigned short u16;
typedef unsigned int u32;

typedef const __attribute__((address_space(1))) void* gas_ptr;
typedef __attribute__((address_space(3))) void* las_ptr;

constexpr int BBATCH = 2;
constexpr int TT  = 1024;
constexpr int BT  = BBATCH * TT;   // 2048 tokens
constexpr int DM  = 1024;
constexpr int NH  = 16;
constexpr int HD  = 64;
constexpr int DFF = 4096;
constexpr int NV  = 32000;
constexpr int NL  = 4;

DEVI u16 f2b(float f) {
  u32 u = __builtin_bit_cast(u32, f);
  u = (u + 0x7fffu + ((u >> 16) & 1u)) >> 16;
  return (u16)u;
}
DEVI float b2f(u16 h) { return __builtin_bit_cast(float, (u32)h << 16); }

DEVI void gld16(const void* g, void* l) {
  __builtin_amdgcn_global_load_lds((gas_ptr)g, (las_ptr)l, 16, 0, 0);
}

DEVI float wave_sum(float v) {
#pragma unroll
  for (int off = 32; off; off >>= 1) v += __shfl_xor(v, off);
  return v;
}
DEVI float block_sum(float v, float* sb) {
  v = wave_sum(v);
  int lane = threadIdx.x & 63, wid = threadIdx.x >> 6;
  __syncthreads();
  if (lane == 0) sb[wid] = v;
  __syncthreads();
  return sb[0] + sb[1] + sb[2] + sb[3];
}

DEVI float gelu_f(float x) {
  float u = 0.7978845608028654f * (x + 0.044715f * x * x * x);
  float e = __expf(2.0f * u);            // gelu = x * sigmoid(2u)
  return x * (1.0f - 1.0f / (e + 1.0f));
}

// ---------------- weight transpose+convert: f32 [K][N] -> bf16 [N][K] ----------------
__global__ __launch_bounds__(256) void wt_transpose(const float* __restrict__ in,
                                                    u16* __restrict__ out, int K, int N) {
  __shared__ float t[32][33];
  int n0 = blockIdx.x * 32, k0 = blockIdx.y * 32;
  int tx = threadIdx.x, ty = threadIdx.y;
#pragma unroll
  for (int i = 0; i < 4; ++i)
    t[ty + 8 * i][tx] = in[(size_t)(k0 + ty + 8 * i) * N + n0 + tx];
  __syncthreads();
#pragma unroll
  for (int i = 0; i < 4; ++i)
    out[(size_t)(n0 + ty + 8 * i) * K + k0 + tx] = f2b(t[tx][ty + 8 * i]);
}

// ---------------- V transpose: qkv bf16 [b*T][3D] (v slice) -> vT [bh][64][1024] ----------------
__global__ __launch_bounds__(256) void v_transpose(const u16* __restrict__ qkv,
                                                   u16* __restrict__ vT) {
  __shared__ u16 t[32][33];
  int bh = blockIdx.z, b = bh >> 4, h = bh & 15;
  int d0 = blockIdx.x * 32, t0 = blockIdx.y * 32;
  int tx = threadIdx.x, ty = threadIdx.y;
  const u16* src = qkv + (size_t)b * TT * 3 * DM + 2 * DM + h * HD;
#pragma unroll
  for (int i = 0; i < 4; ++i)
    t[ty + 8 * i][tx] = src[(size_t)(t0 + ty + 8 * i) * (3 * DM) + d0 + tx];
  __syncthreads();
  u16* dst = vT + (size_t)bh * HD * TT;
#pragma unroll
  for (int i = 0; i < 4; ++i)
    dst[(size_t)(d0 + ty + 8 * i) * TT + t0 + tx] = t[tx][ty + 8 * i];
}

// ---------------- embedding gather + LayerNorm -> x f32 ----------------
__global__ __launch_bounds__(256) void embed_ln_k(const int* __restrict__ idx,
                                                  const float* __restrict__ tok,
                                                  const float* __restrict__ g,
                                                  const float* __restrict__ b,
                                                  float* __restrict__ x) {
  __shared__ float sb[4];
  int row = blockIdx.x, tid = threadIdx.x;
  float4 v = ((const float4*)(tok + (size_t)idx[row] * DM))[tid];
  float s = block_sum(v.x + v.y + v.z + v.w, sb);
  float m = s * (1.0f / DM);
  float dx = v.x - m, dy = v.y - m, dz = v.z - m, dw = v.w - m;
  float q = block_sum(dx * dx + dy * dy + dz * dz + dw * dw, sb);
  float rs = rsqrtf(q * (1.0f / DM) + 1e-5f);
  float4 gg = ((const float4*)g)[tid];
  float4 bb = ((const float4*)b)[tid];
  float4 o = make_float4(dx * rs * gg.x + bb.x, dy * rs * gg.y + bb.y,
                         dz * rs * gg.z + bb.z, dw * rs * gg.w + bb.w);
  ((float4*)(x + (size_t)row * DM))[tid] = o;
}

// ---------------- final LayerNorm -> bf16 ----------------
__global__ __launch_bounds__(256) void final_ln_k(const float* __restrict__ x,
                                                  const float* __restrict__ g,
                                                  const float* __restrict__ b,
                                                  u16* __restrict__ xf) {
  __shared__ float sb[4];
  int row = blockIdx.x, tid = threadIdx.x;
  float4 v = ((const float4*)(x + (size_t)row * DM))[tid];
  float s = block_sum(v.x + v.y + v.z + v.w, sb);
  float m = s * (1.0f / DM);
  float dx = v.x - m, dy = v.y - m, dz = v.z - m, dw = v.w - m;
  float q = block_sum(dx * dx + dy * dy + dz * dz + dw * dw, sb);
  float rs = rsqrtf(q * (1.0f / DM) + 1e-5f);
  float4 gg = ((const float4*)g)[tid];
  float4 bb = ((const float4*)b)[tid];
  u32 lo = (u32)f2b(dx * rs * gg.x + bb.x) | ((u32)f2b(dy * rs * gg.y + bb.y) << 16);
  u32 hi = (u32)f2b(dz * rs * gg.z + bb.z) | ((u32)f2b(dw * rs * gg.w + bb.w) << 16);
  ((uint2*)(xf + (size_t)row * DM))[tid] = make_uint2(lo, hi);
}

// ---------------- RMSNorm f32 -> bf16 ----------------
__global__ __launch_bounds__(256) void rmsnorm_k(const float* __restrict__ x,
                                                 const float* __restrict__ w,
                                                 u16* __restrict__ h) {
  __shared__ float sb[4];
  int row = blockIdx.x, tid = threadIdx.x;
  float4 v = ((const float4*)(x + (size_t)row * DM))[tid];
  float q = block_sum(v.x * v.x + v.y * v.y + v.z * v.z + v.w * v.w, sb);
  float rs = rsqrtf(q * (1.0f / DM) + 1.1920928955078125e-7f);
  float4 ww = ((const float4*)w)[tid];
  u32 lo = (u32)f2b(v.x * rs * ww.x) | ((u32)f2b(v.y * rs * ww.y) << 16);
  u32 hi = (u32)f2b(v.z * rs * ww.z) | ((u32)f2b(v.w * rs * ww.w) << 16);
  ((uint2*)(h + (size_t)row * DM))[tid] = make_uint2(lo, hi);
}

// ---------------- fused flash attention ----------------
// grid (8 q-tiles, 32 bh), 256 threads (4 waves). Wave w owns q-rows
// qt*128 + w*32 .. +31. Q in regs; K/Vt double-buffered LDS; P in per-wave-
// private LDS rows (no barrier between P write and PV read). Online softmax
// in f32 regs. vmcnt ledger: 8 gld16/wave/tile; steady-state wait vmcnt(8),
// last tile vmcnt(0); two barriers per tile (publish staged / protect reuse).
__global__ __launch_bounds__(256) void attn_k(const u16* __restrict__ qkv,
                                              const u16* __restrict__ vT,
                                              u16* __restrict__ y) {
  __shared__ __align__(16) char sP[32768];      // P [128][256B] swz16; Q staged here first
  __shared__ __align__(16) char sK[2][16384];   // K tile [128][128B] swz8
  __shared__ __align__(16) char sV[2][16384];   // Vt tile [64][256B] swz16
  const int tid = threadIdx.x, lane = tid & 63, wid = tid >> 6;
  const int qt = blockIdx.x, bh = blockIdx.y, b = bh >> 4, h = bh & 15;
  const float slope = exp2f(-0.5f * (float)(h + 1));

  const char* Qb = (const char*)(qkv + (size_t)b * TT * 3 * DM + h * HD);
  const char* Kb = (const char*)(qkv + (size_t)b * TT * 3 * DM + DM + h * HD);
  const char* Vb = (const char*)(vT + (size_t)bh * HD * TT);

  // stage own Q rows into sP ([128][128B] layout, swz8)
#pragma unroll
  for (int ci = 0; ci < 4; ++ci) {
    int c = wid * 4 + ci;
    int r = c * 8 + (lane >> 3);
    int q = (lane & 7) ^ (r & 7);
    gld16(Qb + (size_t)(qt * 128 + r) * 6144 + q * 16, sP + c * 1024 + lane * 16);
  }

  auto stageKV = [&](int buf, int kt) {
    int kv0 = kt * 128;
#pragma unroll
    for (int ci = 0; ci < 4; ++ci) {            // K: [128][128B]
      int c = wid * 4 + ci;
      int r = c * 8 + (lane >> 3);
      int q = (lane & 7) ^ (r & 7);
      gld16(Kb + (size_t)(kv0 + r) * 6144 + q * 16, sK[buf] + c * 1024 + lane * 16);
    }
#pragma unroll
    for (int ci = 0; ci < 4; ++ci) {            // Vt: [64][256B]
      int c = wid * 4 + ci;
      int d = c * 4 + (lane >> 4);
      int q = (lane & 15) ^ (d & 15);
      gld16(Vb + (size_t)d * 2048 + (size_t)kv0 * 2 + q * 16, sV[buf] + c * 1024 + lane * 16);
    }
  };
  stageKV(0, 0);
  asm volatile("s_waitcnt vmcnt(8)" ::: "memory");   // Q's 4 loads (oldest) done

  short8 qf[2][2];
#pragma unroll
  for (int i = 0; i < 2; ++i)
#pragma unroll
    for (int ks = 0; ks < 2; ++ks) {
      int r = wid * 32 + i * 16 + (lane & 15);
      int q = ((ks << 2) + (lane >> 4)) ^ (r & 7);
      qf[i][ks] = *(const short8*)(sP + r * 128 + q * 16);
    }

  f32x4 Y[2][4] = {};
  float m_r[2][4], l_r[2][4];
#pragma unroll
  for (int i = 0; i < 2; ++i)
#pragma unroll
    for (int r = 0; r < 4; ++r) { m_r[i][r] = -3e38f; l_r[i][r] = 0.0f; }

  for (int kt = 0; kt <= qt; ++kt) {
    const int cur = kt & 1;
    if (kt < qt) {
      stageKV(cur ^ 1, kt + 1);
      asm volatile("s_waitcnt vmcnt(8)" ::: "memory");
    } else {
      asm volatile("s_waitcnt vmcnt(0)" ::: "memory");
    }
    __syncthreads();   // publish tile kt (and: Q regs loaded before any P write)

    // QK^T
    f32x4 s[2][8] = {};
#pragma unroll
    for (int ks = 0; ks < 2; ++ks) {
      short8 kf[8];
#pragma unroll
      for (int j = 0; j < 8; ++j) {
        int r = j * 16 + (lane & 15);
        int q = ((ks << 2) + (lane >> 4)) ^ (r & 7);
        kf[j] = *(const short8*)(sK[cur] + r * 128 + q * 16);
      }
#pragma unroll
      for (int i = 0; i < 2; ++i)
#pragma unroll
        for (int j = 0; j < 8; ++j)
          s[i][j] = __builtin_amdgcn_mfma_f32_16x16x32_bf16(qf[i][ks], kf[j], s[i][j], 0, 0, 0);
    }

    // scale + ALiBi + causal mask + online softmax (rows private to thread)
    const int kv0 = kt * 128;
#pragma unroll
    for (int i = 0; i < 2; ++i) {
      const int qbase = qt * 128 + wid * 32 + i * 16 + ((lane >> 4) << 2);
      float rowmax[4] = {-3e38f, -3e38f, -3e38f, -3e38f};
#pragma unroll
      for (int j = 0; j < 8; ++j) {
        int kcol = kv0 + j * 16 + (lane & 15);
#pragma unroll
        for (int r = 0; r < 4; ++r) {
          int qrow = qbase + r;
          float v = (kcol <= qrow) ? s[i][j][r] * 0.125f - slope * (float)(qrow - kcol) : -3e38f;
          s[i][j][r] = v;
          rowmax[r] = fmaxf(rowmax[r], v);
        }
      }
#pragma unroll
      for (int r = 0; r < 4; ++r) {
        rowmax[r] = fmaxf(rowmax[r], __shfl_xor(rowmax[r], 1));
        rowmax[r] = fmaxf(rowmax[r], __shfl_xor(rowmax[r], 2));
        rowmax[r] = fmaxf(rowmax[r], __shfl_xor(rowmax[r], 4));
        rowmax[r] = fmaxf(rowmax[r], __shfl_xor(rowmax[r], 8));
        float mn = fmaxf(m_r[i][r], rowmax[r]);
        float al = __expf(m_r[i][r] - mn);
        m_r[i][r] = mn;
        l_r[i][r] *= al;
#pragma unroll
        for (int j = 0; j < 4; ++j) Y[i][j][r] *= al;
      }
      float rs[4] = {0.0f, 0.0f, 0.0f, 0.0f};
#pragma unroll
      for (int j = 0; j < 8; ++j)
#pragma unroll
        for (int r = 0; r < 4; ++r) {
          float p = __expf(s[i][j][r] - m_r[i][r]);
          s[i][j][r] = p;
          rs[r] += p;
        }
#pragma unroll
      for (int r = 0; r < 4; ++r) {
        rs[r] += __shfl_xor(rs[r], 1);
        rs[r] += __shfl_xor(rs[r], 2);
        rs[r] += __shfl_xor(rs[r], 4);
        rs[r] += __shfl_xor(rs[r], 8);
        l_r[i][r] += rs[r];
      }
      // write P (bf16) to own sP rows, swz16 over 256B rows
#pragma unroll
      for (int j = 0; j < 8; ++j)
#pragma unroll
        for (int r = 0; r < 4; ++r) {
          int rl = wid * 32 + i * 16 + ((lane >> 4) << 2) + r;
          int c = j * 16 + (lane & 15);
          int g = c >> 3;
          *(u16*)(sP + rl * 256 + ((g ^ (rl & 15)) << 4) + (c & 7) * 2) = f2b(s[i][j][r]);
        }
    }

    // PV: Y += P(own rows) * Vt
#pragma unroll
    for (int ks = 0; ks < 4; ++ks) {
      short8 pf[2], vf[4];
#pragma unroll
      for (int i = 0; i < 2; ++i) {
        int r = wid * 32 + i * 16 + (lane & 15);
        int q = ((ks << 2) + (lane >> 4)) ^ (r & 15);
        pf[i] = *(const short8*)(sP + r * 256 + (q << 4));
      }
#pragma unroll
      for (int j = 0; j < 4; ++j) {
        int d = j * 16 + (lane & 15);
        int q = ((ks << 2) + (lane >> 4)) ^ (d & 15);
        vf[j] = *(const short8*)(sV[cur] + d * 256 + (q << 4));
      }
#pragma unroll
      for (int i = 0; i < 2; ++i)
#pragma unroll
        for (int j = 0; j < 4; ++j)
          Y[i][j] = __builtin_amdgcn_mfma_f32_16x16x32_bf16(pf[i], vf[j], Y[i][j], 0, 0, 0);
    }
    __syncthreads();   // all waves done with bufs[cur] before next stage overwrites
  }

  // epilogue: y[b, qrow, h*64 + d] = Y / l
#pragma unroll
  for (int i = 0; i < 2; ++i)
#pragma unroll
    for (int r = 0; r < 4; ++r) {
      float inv = 1.0f / l_r[i][r];
      int qrow = qt * 128 + wid * 32 + i * 16 + ((lane >> 4) << 2) + r;
      u16* yp = y + (size_t)(b * TT + qrow) * DM + h * HD;
#pragma unroll
      for (int j = 0; j < 4; ++j)
        yp[j * 16 + (lane & 15)] = f2b(Y[i][j][r] * inv);
    }
}

// ---------------- GEMM epilogue variants ----------------
enum { EPI_BF16 = 0, EPI_GELU = 1, EPI_ADDF32 = 2, EPI_F32 = 3 };

// ---------------- 2-phase 128-tile GEMM (validated r1) ----------------
template <int BM, int BN, int WM, int WN, int EPI>
__global__ __launch_bounds__(256, 2) void gemm_bt(
    const u16* __restrict__ A, int lda, const u16* __restrict__ Bt, int ldb,
    const float* __restrict__ bias, void* __restrict__ C, int ldc,
    float* __restrict__ resid, int K) {
  constexpr int BK = 64;
  constexpr int NW = WM * WN;
  constexpr int FM = BM / WM / 16, FN = BN / WN / 16;
  constexpr int ABYTES = BM * BK * 2, BBYTES = BN * BK * 2;
  constexpr int ACH = ABYTES / 1024, BCH = BBYTES / 1024, NCH = ACH + BCH;
  extern __shared__ __align__(16) char smem[];

  const int tid = threadIdx.x, lane = tid & 63, wid = tid >> 6;
  const int brow = blockIdx.y * BM, bcol = blockIdx.x * BN;

  const int nt = K >> 6;
  const int widm = wid / WN, widn = wid % WN;
  const int rm0 = widm * (BM / WM), cn0 = widn * (BN / WN);

  f32x4 acc[FM][FN] = {};

  const int swq16 = (((lane & 7) ^ ((lane >> 3) & 7)) << 4);
  const int lrow8 = lane >> 3;

  auto stage = [&](int buf, int kt) {
    char* base = smem + buf * (ABYTES + BBYTES);
    const char* Ag = (const char*)A;
    const char* Bg = (const char*)Bt;
    long long kOff = (long long)kt * 128 + swq16;
#pragma unroll
    for (int ci = 0; ci < NCH / NW; ++ci) {
      int c = wid + ci * NW;
      if (c < ACH) {
        int r = c * 8 + lrow8;
        gld16(Ag + (long long)(brow + r) * (lda * 2) + kOff, base + c * 1024 + lane * 16);
      } else {
        int r = (c - ACH) * 8 + lrow8;
        gld16(Bg + (long long)(bcol + r) * (ldb * 2) + kOff,
              base + ABYTES + (c - ACH) * 1024 + lane * 16);
      }
    }
  };

  auto compute = [&](int buf) {
    char* baseA = smem + buf * (ABYTES + BBYTES);
    char* baseB = baseA + ABYTES;
#pragma unroll
    for (int ks = 0; ks < 2; ++ks) {
      short8 af[FM], bv[FN];
#pragma unroll
      for (int i = 0; i < FM; ++i) {
        int r = rm0 + i * 16 + (lane & 15);
        int cq = ((ks << 2) + (lane >> 4)) ^ (r & 7);
        af[i] = *(const short8*)(baseA + r * 128 + (cq << 4));
      }
#pragma unroll
      for (int j = 0; j < FN; ++j) {
        int r = cn0 + j * 16 + (lane & 15);
        int cq = ((ks << 2) + (lane >> 4)) ^ (r & 7);
        bv[j] = *(const short8*)(baseB + r * 128 + (cq << 4));
      }
#pragma unroll
      for (int i = 0; i < FM; ++i)
#pragma unroll
        for (int j = 0; j < FN; ++j)
          acc[i][j] = __builtin_amdgcn_mfma_f32_16x16x32_bf16(af[i], bv[j], acc[i][j], 0, 0, 0);
    }
  };

  stage(0, 0);
  __syncthreads();
  int cur = 0;
  for (int t = 0; t < nt; ++t) {
    if (t + 1 < nt) stage(cur ^ 1, t + 1);
    compute(cur);
    __syncthreads();
    cur ^= 1;
  }

  const int r0 = brow + rm0 + ((lane >> 4) << 2);
  const int c0 = bcol + cn0 + (lane & 15);
#pragma unroll
  for (int i = 0; i < FM; ++i) {
#pragma unroll
    for (int j = 0; j < FN; ++j) {
#pragma unroll
      for (int r = 0; r < 4; ++r) {
        int row = r0 + i * 16 + r;
        int col = c0 + j * 16;
        float v = acc[i][j][r];
        if constexpr (EPI == EPI_BF16) {
          ((u16*)C)[(size_t)row * ldc + col] = f2b(v + bias[col]);
        } else if constexpr (EPI == EPI_GELU) {
          ((u16*)C)[(size_t)row * ldc + col] = f2b(gelu_f(v + bias[col]));
        } else if constexpr (EPI == EPI_ADDF32) {
          size_t o = (size_t)row * ldc + col;
          resid[o] += v + bias[col];
        } else {
          ((float*)C)[(size_t)row * ldc + col] = v + bias[col];
        }
      }
    }
  }
}

// ---------------- 8-phase 256x256 GEMM (T1+T2+T3+T4+T5) — LM head ----------------
template <int EPI>
__global__ __launch_bounds__(512, 2) void gemm8(
    const u16* __restrict__ A, int lda, const u16* __restrict__ Bt, int ldb,
    const float* __restrict__ bias, void* __restrict__ C, int ldc, int K, int nby) {
  __shared__ __align__(16) char smem[2][2][32768];
  const int tid = threadIdx.x, lane = tid & 63;
  const int wid = tid >> 6, wm = wid >> 2, wn = wid & 3;

  const int nb = gridDim.x;
  const int q8 = nb >> 3, r8 = nb & 7;
  const int xcd = blockIdx.x & 7, lin = blockIdx.x >> 3;
  const int idx = (xcd < r8 ? xcd * (q8 + 1) : r8 * (q8 + 1) + (xcd - r8) * q8) + lin;
  const int brow = (idx % nby) * 256, bcol = (idx / nby) * 256;

  const int nt = K >> 6, niter = nt >> 1;

  const int srow = tid >> 3, sq = tid & 7;
  auto stage = [&](int buf, int isB, int half, int kt) {
    const u16* G = isB ? Bt : A;
    const int ld = isB ? ldb : lda;
    const int base = isB ? bcol : brow;
    char* L = &smem[buf][isB][half * 16384];
#pragma unroll
    for (int l = 0; l < 2; ++l) {
      int rl = half * 128 + l * 64 + srow;
      gld16((const char*)G + (size_t)(base + rl) * (ld * 2) + kt * 128 + ((sq ^ (rl & 7)) << 4),
            L + l * 8192 + tid * 16);
    }
  };

  short8 bfr[4][2], afr[2][2];
  f32x4 acc[8][4] = {};

  stage(0, 0, 0, 0); stage(0, 0, 1, 0);
  stage(0, 1, 0, 0); stage(0, 1, 1, 0);
  stage(1, 1, 0, 1); stage(1, 1, 1, 1);
  asm volatile("s_waitcnt vmcnt(0)" ::: "memory");
  __builtin_amdgcn_s_barrier();

  for (int i = 0; i < niter; ++i) {
    const bool full = (i + 1 < niter);
    const int t2 = 2 * i + 2, t3 = 2 * i + 3;
#pragma unroll
    for (int h = 0; h < 2; ++h) {
#pragma unroll
      for (int qd = 0; qd < 4; ++qd) {
        if (qd == 0) {
#pragma unroll
          for (int j = 0; j < 4; ++j)
#pragma unroll
            for (int ks = 0; ks < 2; ++ks) {
              int r = wn * 64 + j * 16 + (lane & 15);
              int q = ((ks << 2) + (lane >> 4)) ^ (r & 7);
              bfr[j][ks] = *(const short8*)&smem[h][1][r * 128 + q * 16];
            }
        }
#pragma unroll
        for (int f = 0; f < 2; ++f)
#pragma unroll
          for (int ks = 0; ks < 2; ++ks) {
            int r = wm * 128 + (qd * 2 + f) * 16 + (lane & 15);
            int q = ((ks << 2) + (lane >> 4)) ^ (r & 7);
            afr[f][ks] = *(const short8*)&smem[h][0][r * 128 + q * 16];
          }
        if (h == 0) {
          if (qd == 0) stage(1, 0, 0, 2 * i + 1);
          else if (qd == 1) stage(1, 0, 1, 2 * i + 1);
          else if (qd == 2) { if (full) stage(0, 1, 0, t2); }
          else              { if (full) stage(0, 1, 1, t2); }
        } else {
          if (qd == 0)      { if (full) stage(0, 0, 0, t2); }
          else if (qd == 1) { if (full) stage(0, 0, 1, t2); }
          else if (qd == 2) { if (full) stage(1, 1, 0, t3); }
          else              { if (full) stage(1, 1, 1, t3); }
        }
        if (qd == 3) {
          if (full) asm volatile("s_waitcnt vmcnt(4)" ::: "memory");
          else if (h == 0) asm volatile("s_waitcnt vmcnt(0)" ::: "memory");
        }
        __builtin_amdgcn_s_barrier();
        asm volatile("s_waitcnt lgkmcnt(0)" ::: "memory");
        __builtin_amdgcn_s_setprio(1);
#pragma unroll
        for (int f = 0; f < 2; ++f)
#pragma unroll
          for (int j = 0; j < 4; ++j)
#pragma unroll
            for (int ks = 0; ks < 2; ++ks)
              acc[qd * 2 + f][j] = __builtin_amdgcn_mfma_f32_16x16x32_bf16(
                  afr[f][ks], bfr[j][ks], acc[qd * 2 + f][j], 0, 0, 0);
        __builtin_amdgcn_s_setprio(0);
        __builtin_amdgcn_s_barrier();
      }
    }
  }

  const int r0 = brow + wm * 128 + ((lane >> 4) << 2);
  const int c0 = bcol + wn * 64 + (lane & 15);
#pragma unroll
  for (int fi = 0; fi < 8; ++fi) {
#pragma unroll
    for (int j = 0; j < 4; ++j) {
      int col = c0 + j * 16;
      float bv = bias[col];
#pragma unroll
      for (int r = 0; r < 4; ++r) {
        int row = r0 + fi * 16 + r;
        float v = acc[fi][j][r] + bv;
        if constexpr (EPI == EPI_F32)
          ((float*)C)[(size_t)row * ldc + col] = v;
        else if constexpr (EPI == EPI_GELU)
          ((u16*)C)[(size_t)row * ldc + col] = f2b(gelu_f(v));
        else
          ((u16*)C)[(size_t)row * ldc + col] = f2b(v);
      }
    }
  }
}

extern "C" void kernel_launch(void* const* d_in, const int* in_sizes, int n_in,
                              void* d_out, int out_size, void* d_ws, size_t ws_size,
                              hipStream_t stream) {
  (void)in_sizes; (void)n_in; (void)out_size;
  const int*   idx    = (const int*)d_in[0];
  const float* tok    = (const float*)d_in[1];
  const float* ln_e_g = (const float*)d_in[2];
  const float* ln_e_b = (const float*)d_in[3];
  const float* Wqkv   = (const float*)d_in[4];
  const float* bqkv   = (const float*)d_in[5];
  const float* Wo     = (const float*)d_in[6];
  const float* bo     = (const float*)d_in[7];
  const float* W1     = (const float*)d_in[8];
  const float* b1     = (const float*)d_in[9];
  const float* W2     = (const float*)d_in[10];
  const float* b2     = (const float*)d_in[11];
  const float* n1_w   = (const float*)d_in[12];
  const float* n2_w   = (const float*)d_in[13];
  const float* lnf_g  = (const float*)d_in[14];
  const float* lnf_b  = (const float*)d_in[15];
  const float* Wlm    = (const float*)d_in[16];
  const float* blm    = (const float*)d_in[17];
  float* out = (float*)d_out;

  char* w = (char*)d_ws;
  auto alloc = [&](size_t bytes) { char* p = w; w += (bytes + 255) & ~(size_t)255; return p; };
  float* x   = (float*)alloc((size_t)BT * DM * 4);
  u16* h     = (u16*)alloc((size_t)BT * DM * 2);
  u16* qkv   = (u16*)alloc((size_t)BT * 3 * DM * 2);
  u16* vT    = (u16*)alloc((size_t)BBATCH * NH * HD * TT * 2);
  u16* y     = (u16*)alloc((size_t)BT * DM * 2);
  u16* act   = (u16*)alloc((size_t)BT * DFF * 2);
  u16* xf    = (u16*)alloc((size_t)BT * DM * 2);
  u16* WqkvT = (u16*)alloc((size_t)3 * DM * DM * 2);
  u16* WoT   = (u16*)alloc((size_t)DM * DM * 2);
  u16* W1T   = (u16*)alloc((size_t)DFF * DM * 2);
  u16* W2T   = (u16*)alloc((size_t)DM * DFF * 2);
  u16* WlmT  = (u16*)alloc((size_t)NV * DM * 2);
  if ((size_t)(w - (char*)d_ws) > ws_size) return;

  dim3 t328(32, 8);
  wt_transpose<<<dim3(3 * DM / 32, DM / 32), t328, 0, stream>>>(Wqkv, WqkvT, DM, 3 * DM);
  wt_transpose<<<dim3(DM / 32, DM / 32), t328, 0, stream>>>(Wo, WoT, DM, DM);
  wt_transpose<<<dim3(DFF / 32, DM / 32), t328, 0, stream>>>(W1, W1T, DM, DFF);
  wt_transpose<<<dim3(DM / 32, DFF / 32), t328, 0, stream>>>(W2, W2T, DFF, DM);
  wt_transpose<<<dim3(NV / 32, DM / 32), t328, 0, stream>>>(Wlm, WlmT, DM, NV);

  embed_ln_k<<<BT, 256, 0, stream>>>(idx, tok, ln_e_g, ln_e_b, x);

  constexpr int SM128 = 2 * (128 * 64 * 2 + 128 * 64 * 2);  // 65536

  for (int l = 0; l < NL; ++l) {
    rmsnorm_k<<<BT, 256, 0, stream>>>(x, n1_w, h);
    gemm_bt<128, 128, 2, 2, EPI_BF16><<<dim3(3 * DM / 128, BT / 128), 256, SM128, stream>>>(
        h, DM, WqkvT, DM, bqkv, qkv, 3 * DM, nullptr, DM);
    v_transpose<<<dim3(HD / 32, TT / 32, BBATCH * NH), t328, 0, stream>>>(qkv, vT);
    attn_k<<<dim3(TT / 128, BBATCH * NH), 256, 0, stream>>>(qkv, vT, y);
    gemm_bt<128, 128, 2, 2, EPI_ADDF32><<<dim3(DM / 128, BT / 128), 256, SM128, stream>>>(
        y, DM, WoT, DM, bo, nullptr, DM, x, DM);
    rmsnorm_k<<<BT, 256, 0, stream>>>(x, n2_w, h);
    gemm_bt<128, 128, 2, 2, EPI_GELU><<<dim3(DFF / 128, BT / 128), 256, SM128, stream>>>(
        h, DM, W1T, DM, b1, act, DFF, nullptr, DM);
    gemm_bt<128, 128, 2, 2, EPI_ADDF32><<<dim3(DM / 128, BT / 128), 256, SM128, stream>>>(
        act, DFF, W2T, DFF, b2, nullptr, DM, x, DFF);
  }

  final_ln_k<<<BT, 256, 0, stream>>>(x, lnf_g, lnf_b, xf);
  gemm8<EPI_F32><<<dim3((NV / 256) * (BT / 256)), 512, 0, stream>>>(
      xf, DM, WlmT, DM, blm, out, NV, DM, BT / 256);
}